// Round 8
// baseline (783.642 us; speedup 1.0000x reference)
//
#include <hip/hip_runtime.h>

typedef unsigned short ushort_t;
typedef unsigned int uint_t;
typedef unsigned long long ull_t;
typedef __attribute__((ext_vector_type(8))) short bf16x8;
typedef __attribute__((ext_vector_type(4))) float f32x4;
typedef __attribute__((ext_vector_type(2))) float f32x2;

#define N_NODES 50000
#define N_EDGES 800000
#define BN_EPS 1e-5f

// ws layout (floats): [0 .. 4800000) h buffer   [4800000..4801536) BN stats
//                     (8 replicas x 192)        [4801536] edge dtype flag
#define OFF_STATS 4800000
#define OFF_FLAG  4801536
#define NREP 8

// region binning: 64 nodes/region
#define RBITS 6
#define RNODES 64
#define NREG 782           // ceil(50000/64)
#define SLAB 2048          // slots/region (mean ~1024, binomial sd ~32)
#define RSTRIDE 16         // ints per cursor slot (64B spread)

// scratch carved out of d_out (ints) — consumed before bn writes out:
#define SC_SLAB 0                       // int2[NREG*SLAB] = 12.8 MB
#define SC_RCUR (NREG * SLAB * 2)       // int[NREG*RSTRIDE]

#define MTILE 64
#define NTILES ((N_NODES + MTILE - 1) / MTILE)  // 782

__device__ __forceinline__ ushort_t f2bf(float f) {
    uint_t u = __float_as_uint(f);
    uint_t r = ((u >> 16) & 1u) + 0x7fffu;  // RNE
    return (ushort_t)((u + r) >> 16);
}

// native LDS float atomic add. Generic pointer to LDS on gfx9+: low 32 bits
// are the LDS byte offset (shared aperture is 4GB-aligned). ds_add_f32 is
// fire-and-forget (no return), lgkmcnt-tracked only via manual drain below.
__device__ __forceinline__ void lds_fadd(float* p, float v) {
    asm volatile("ds_add_f32 %0, %1"
                 :: "v"((uint_t)(size_t)p), "v"(v) : "memory");
}

// ---------------------------------------------------------------------------
// init: zero region cursors + stats replicas; block 0 detects int64 vs int32.
// ---------------------------------------------------------------------------
__global__ __launch_bounds__(256) void init_kernel(const int* __restrict__ ei,
                                                   int* __restrict__ flag,
                                                   int* __restrict__ rcur,
                                                   float* __restrict__ stats) {
    const int gtid = blockIdx.x * 256 + threadIdx.x;
    const int nth = gridDim.x * 256;
    for (int i = gtid; i < NREG * RSTRIDE; i += nth) rcur[i] = 0;
    if (gtid < NREP * 192) stats[gtid] = 0.f;
    if (blockIdx.x == 0) {
        __shared__ int s_any;
        if (threadIdx.x == 0) s_any = 0;
        __syncthreads();
        int nz = 0;
#pragma unroll
        for (int j = 0; j < 16; ++j) {
            const int p = 1 + 2 * (threadIdx.x * 16 + j) * 195;  // odd, <1.6M
            if (ei[p] != 0) nz = 1;
        }
        if (nz) atomicOr(&s_any, 1);
        __syncthreads();
        if (threadIdx.x == 0) *flag = s_any ? 0 : 1;
    }
}

// ---------------------------------------------------------------------------
// bin: single pass over edges. region r = dst>>6; pos = rcur[r]++ (atomic);
// slab[r*SLAB+pos] = {x=src, y=eid | dlocal<<20}. NT store. Replaces
// hist+scan+scatter (3 passes, 1.6M atomics) with 1 pass, 800K atomics.
// ---------------------------------------------------------------------------
__global__ __launch_bounds__(256) void bin_kernel(const int* __restrict__ ei,
                                                  const int* __restrict__ flag,
                                                  int* __restrict__ rcur,
                                                  int2* __restrict__ slab) {
    const int is64 = *flag;
    const int stride = gridDim.x * blockDim.x;
    for (int e = blockIdx.x * blockDim.x + threadIdx.x; e < N_EDGES; e += stride) {
        int s, d;
        if (is64) { s = ei[2 * e]; d = ei[2 * N_EDGES + 2 * e]; }
        else      { s = ei[e];     d = ei[N_EDGES + e]; }
        if ((uint_t)s < N_NODES && (uint_t)d < N_NODES) {
            const int r = d >> RBITS;
            const int dl = d & (RNODES - 1);
            const int pos = atomicAdd(&rcur[r * RSTRIDE], 1);
            if (pos < SLAB) {
                const uint_t packed = (uint_t)e | ((uint_t)dl << 20);
                const ull_t v = ((ull_t)packed << 32) | (uint_t)s;  // {x=s,y=packed}
                __builtin_nontemporal_store(v,
                    (ull_t*)&slab[(size_t)r * SLAB + pos]);
            }
        }
    }
}

// ---------------------------------------------------------------------------
// region_aggr: block = 64-node region, LDS accumulator h[64][100].
// Edge tiles packed 16-dense from region list. Per tile:
//   proj[16e x 96f] = ea[eids] @ We via 6x mfma 16x16x32 bf16
//   (A[m=t][k=q*8+j], C row m=q*4+r col t  [m89 layout])
//   msg = relu(proj + be + x[src]) -> native ds_add_f32 into h[dl][*]
// Writeout: hbuf[n] = h[dl] + x[n], coalesced. No global float atomics.
// ONLY change vs round 7: unsafeAtomicAdd (flat/CAS path, 530us) replaced by
// native ds_add_f32 inline asm + explicit lgkmcnt drain.
// ---------------------------------------------------------------------------
__global__ __launch_bounds__(256) void region_aggr_kernel(
    const float* __restrict__ x, const float* __restrict__ ea,
    const float* __restrict__ We, const float* __restrict__ be,
    const int2* __restrict__ slab, const int* __restrict__ rcur,
    float* __restrict__ hbuf) {
    __shared__ float h[RNODES][100];

    const int tid = threadIdx.x;
    const int r = blockIdx.x;
    for (int i = tid; i < RNODES * 100 / 4; i += 256) {
        f32x4 z = {0.f, 0.f, 0.f, 0.f};
        ((f32x4*)&h[0][0])[i] = z;
    }

    const int lane = tid & 63;
    const int q = lane >> 4;
    const int t = lane & 15;
    const int w = tid >> 6;  // wave 0..3

    bf16x8 Bf[6];
    float ben[6];
#pragma unroll
    for (int f = 0; f < 6; ++f) {
        const int n = t + 16 * f;
#pragma unroll
        for (int j = 0; j < 8; ++j) {
            const int k = q * 8 + j;
            Bf[f][j] = (short)f2bf(We[k * 96 + n]);
        }
        ben[f] = be[n];
    }

    int cnt = rcur[r * RSTRIDE];
    if (cnt > SLAB) cnt = SLAB;
    const int2* lst = slab + (size_t)r * SLAB;
    const int ntile = (cnt + 15) >> 4;

    __syncthreads();  // h zeroed

    for (int tile = w; tile < ntile; tile += 4) {
        const int base = tile * 16;
        const int rem = cnt - base;  // >= 1
        int eid = -1, src = -1, dl = 0;
        if (t < rem) {
            const int2 p = lst[base + t];
            src = p.x;
            eid = (int)((uint_t)p.y & 0xFFFFFu);
            dl = (int)((uint_t)p.y >> 20);
        }
        bf16x8 A = {0, 0, 0, 0, 0, 0, 0, 0};
        if (eid >= 0) {
            const float* row = ea + (size_t)eid * 32 + q * 8;
            f32x4 a0 = *(const f32x4*)(row);
            f32x4 a1 = *(const f32x4*)(row + 4);
#pragma unroll
            for (int j = 0; j < 4; ++j) {
                A[j] = (short)f2bf(a0[j]);
                A[4 + j] = (short)f2bf(a1[j]);
            }
        }

        f32x4 acc[6];
#pragma unroll
        for (int f = 0; f < 6; ++f) {
            f32x4 z = {0.f, 0.f, 0.f, 0.f};
            acc[f] = __builtin_amdgcn_mfma_f32_16x16x32_bf16(A, Bf[f], z, 0, 0, 0);
        }

#pragma unroll
        for (int rr = 0; rr < 4; ++rr) {
            const int m = q * 4 + rr;
            const int s_m = __shfl(src, m);
            const int dl_m = __shfl(dl, m);
            if (m < rem) {
                const float* xrow = x + (size_t)s_m * 96;
#pragma unroll
                for (int f = 0; f < 6; ++f) {
                    float v = acc[f][rr] + ben[f] + xrow[t + 16 * f];
                    v = v > 0.f ? v : 0.f;
                    lds_fadd(&h[dl_m][t + 16 * f], v);
                }
            }
        }
    }

    // inline-asm ds ops are not tracked by the compiler's waitcnt insertion:
    // drain explicitly before the barrier that guards the read phase.
    asm volatile("s_waitcnt lgkmcnt(0)" ::: "memory");
    __syncthreads();  // all tiles accumulated

    const int n0 = r * RNODES;
    for (int i = tid; i < RNODES * 96 / 4; i += 256) {
        const int idx = i * 4;
        const int dl = idx / 96;
        const int c = idx - dl * 96;
        const int n = n0 + dl;
        if (n < N_NODES) {
            f32x4 hv = *(const f32x4*)&h[dl][c];
            const f32x4 xv = *(const f32x4*)(x + (size_t)n * 96 + c);
            hv[0] += xv[0]; hv[1] += xv[1]; hv[2] += xv[2]; hv[3] += xv[3];
            *(f32x4*)(hbuf + (size_t)n * 96 + c) = hv;
        }
    }
}

// ---------------------------------------------------------------------------
// mlp: 64-node tile, 256 threads, fp32 register-tiled.
// stats atomics striped over NREP replicas to break line contention.
// ---------------------------------------------------------------------------
__global__ __launch_bounds__(256) void mlp_kernel(
    float* buf, const float* __restrict__ W1g, const float* __restrict__ b1g,
    const float* __restrict__ W2g, const float* __restrict__ b2g,
    float* __restrict__ stats) {
    __shared__ float Ws[96 * 96];
    __shared__ float hsT[96][68];

    const int tid = threadIdx.x;
    const int fg = tid & 15;
    const int ng = tid >> 4;
    const int n0 = blockIdx.x * MTILE;

    for (int i = tid; i < 96 * 96 / 4; i += 256)
        ((f32x4*)Ws)[i] = ((const f32x4*)W1g)[i];
    for (int i = tid; i < MTILE * 96 / 4; i += 256) {
        const int base = i * 4;
        const int nn = base / 96, k = base - nn * 96;
        f32x4 v = {0.f, 0.f, 0.f, 0.f};
        if (n0 + nn < N_NODES)
            v = *(const f32x4*)(buf + (size_t)(n0 + nn) * 96 + k);
        hsT[k][nn] = v[0]; hsT[k + 1][nn] = v[1];
        hsT[k + 2][nn] = v[2]; hsT[k + 3][nn] = v[3];
    }
    __syncthreads();

    float acc[4][6];
#pragma unroll
    for (int ff = 0; ff < 6; ++ff) {
        const float b = b1g[6 * fg + ff];
        acc[0][ff] = b; acc[1][ff] = b; acc[2][ff] = b; acc[3][ff] = b;
    }
    for (int k = 0; k < 96; ++k) {
        const f32x4 a = *(const f32x4*)&hsT[k][4 * ng];
        const float* wr = &Ws[k * 96 + 6 * fg];
        const f32x2 w01 = *(const f32x2*)(wr);
        const f32x2 w23 = *(const f32x2*)(wr + 2);
        const f32x2 w45 = *(const f32x2*)(wr + 4);
        const float w[6] = {w01[0], w01[1], w23[0], w23[1], w45[0], w45[1]};
#pragma unroll
        for (int nn = 0; nn < 4; ++nn)
#pragma unroll
            for (int ff = 0; ff < 6; ++ff) acc[nn][ff] += a[nn] * w[ff];
    }
    __syncthreads();

#pragma unroll
    for (int nn = 0; nn < 4; ++nn)
#pragma unroll
        for (int ff = 0; ff < 6; ++ff) {
            float v = acc[nn][ff];
            hsT[6 * fg + ff][4 * ng + nn] = v > 0.f ? v : 0.f;
        }
    for (int i = tid; i < 96 * 96 / 4; i += 256)
        ((f32x4*)Ws)[i] = ((const f32x4*)W2g)[i];
    __syncthreads();

#pragma unroll
    for (int ff = 0; ff < 6; ++ff) {
        const float b = b2g[6 * fg + ff];
        acc[0][ff] = b; acc[1][ff] = b; acc[2][ff] = b; acc[3][ff] = b;
    }
    for (int k = 0; k < 96; ++k) {
        const f32x4 a = *(const f32x4*)&hsT[k][4 * ng];
        const float* wr = &Ws[k * 96 + 6 * fg];
        const f32x2 w01 = *(const f32x2*)(wr);
        const f32x2 w23 = *(const f32x2*)(wr + 2);
        const f32x2 w45 = *(const f32x2*)(wr + 4);
        const float w[6] = {w01[0], w01[1], w23[0], w23[1], w45[0], w45[1]};
#pragma unroll
        for (int nn = 0; nn < 4; ++nn)
#pragma unroll
            for (int ff = 0; ff < 6; ++ff) acc[nn][ff] += a[nn] * w[ff];
    }

#pragma unroll
    for (int nn = 0; nn < 4; ++nn) {
        const int n = n0 + 4 * ng + nn;
        if (n < N_NODES) {
            float* o = buf + (size_t)n * 96 + 6 * fg;
            *(f32x2*)(o)     = (f32x2){acc[nn][0], acc[nn][1]};
            *(f32x2*)(o + 2) = (f32x2){acc[nn][2], acc[nn][3]};
            *(f32x2*)(o + 4) = (f32x2){acc[nn][4], acc[nn][5]};
        }
    }

    __syncthreads();
#pragma unroll
    for (int nn = 0; nn < 4; ++nn)
#pragma unroll
        for (int ff = 0; ff < 6; ++ff)
            hsT[6 * fg + ff][4 * ng + nn] = acc[nn][ff];
    __syncthreads();

    if (tid < 96) {
        int nmax = N_NODES - n0;
        if (nmax > MTILE) nmax = MTILE;
        float s = 0.f, s2 = 0.f;
        for (int n = 0; n < nmax; ++n) {
            const float v = hsT[tid][n];
            s += v; s2 += v * v;
        }
        float* st = stats + (blockIdx.x & (NREP - 1)) * 192;
        atomicAdd(&st[tid], s);
        atomicAdd(&st[96 + tid], s2);
    }
}

// ---------------------------------------------------------------------------
// bn: sum stat replicas, finalize + affine + ReLU, float4 streaming.
// ---------------------------------------------------------------------------
__global__ __launch_bounds__(256) void bn_kernel(
    const float* __restrict__ h2, const float* __restrict__ stats,
    const float* __restrict__ gamma, const float* __restrict__ beta,
    float* __restrict__ out) {
    __shared__ float sc[96], sh[96];
    const int tid = threadIdx.x;
    if (tid < 96) {
        float s1 = 0.f, s2 = 0.f;
#pragma unroll
        for (int r = 0; r < NREP; ++r) {
            s1 += stats[r * 192 + tid];
            s2 += stats[r * 192 + 96 + tid];
        }
        const float inv_n = 1.f / (float)N_NODES;
        const float mean = s1 * inv_n;
        float var = s2 * inv_n - mean * mean;
        var = var > 0.f ? var : 0.f;
        const float s = gamma[tid] * rsqrtf(var + BN_EPS);
        sc[tid] = s;
        sh[tid] = beta[tid] - mean * s;
    }
    __syncthreads();
    const int total4 = N_NODES * 96 / 4;
    for (int i = blockIdx.x * blockDim.x + tid; i < total4;
         i += gridDim.x * blockDim.x) {
        f32x4 v = ((const f32x4*)h2)[i];
        const int jb = (i * 4) % 96;
#pragma unroll
        for (int c = 0; c < 4; ++c) {
            float u = v[c] * sc[jb + c] + sh[jb + c];
            v[c] = u > 0.f ? u : 0.f;
        }
        ((f32x4*)out)[i] = v;
    }
}

// ---------------------------------------------------------------------------
extern "C" void kernel_launch(void* const* d_in, const int* in_sizes, int n_in,
                              void* d_out, int out_size, void* d_ws,
                              size_t ws_size, hipStream_t stream) {
    const float* x     = (const float*)d_in[0];
    const int*   ei    = (const int*)d_in[1];
    const float* ea    = (const float*)d_in[2];
    const float* We    = (const float*)d_in[3];
    const float* be    = (const float*)d_in[4];
    const float* W1    = (const float*)d_in[5];
    const float* b1    = (const float*)d_in[6];
    const float* W2    = (const float*)d_in[7];
    const float* b2    = (const float*)d_in[8];
    const float* gamma = (const float*)d_in[9];
    const float* beta  = (const float*)d_in[10];
    float* out = (float*)d_out;

    float* ws    = (float*)d_ws;
    float* hbuf  = ws;
    float* stats = ws + OFF_STATS;
    int*   flagp = (int*)(ws + OFF_FLAG);

    int*  scratch = (int*)d_out;
    int2* slab    = (int2*)(scratch + SC_SLAB);
    int*  rcur    = scratch + SC_RCUR;

    init_kernel<<<64, 256, 0, stream>>>(ei, flagp, rcur, stats);
    bin_kernel<<<1024, 256, 0, stream>>>(ei, flagp, rcur, slab);
    region_aggr_kernel<<<NREG, 256, 0, stream>>>(x, ea, We, be, slab, rcur,
                                                 hbuf);
    mlp_kernel<<<NTILES, 256, 0, stream>>>(hbuf, W1, b1, W2, b2, stats);
    bn_kernel<<<1024, 256, 0, stream>>>(hbuf, stats, gamma, beta, out);
}

// Round 9
// 772.909 us; speedup vs baseline: 1.0139x; 1.0139x over previous
//
#include <hip/hip_runtime.h>

typedef unsigned short ushort_t;
typedef unsigned int uint_t;
typedef unsigned long long ull_t;
typedef __attribute__((ext_vector_type(8))) short bf16x8;
typedef __attribute__((ext_vector_type(4))) float f32x4;
typedef __attribute__((ext_vector_type(2))) float f32x2;

#define N_NODES 50000
#define N_EDGES 800000
#define BN_EPS 1e-5f

// ws layout (floats): [0 .. 4800000) h buffer   [4800000..4801536) BN stats
//                     (8 replicas x 192)        [4801536] edge dtype flag
#define OFF_STATS 4800000
#define OFF_FLAG  4801536
#define NREP 8

// region binning: 64 nodes/region
#define RBITS 6
#define RNODES 64
#define NREG 782           // ceil(50000/64)
#define SLAB 2048          // slots/region (mean ~1024, binomial sd ~32)
#define RSTRIDE 16         // ints per cursor slot (64B spread)

// scratch carved out of d_out (ints) — consumed before bn writes out:
#define SC_SLAB 0                       // int2[NREG*SLAB] = 12.8 MB
#define SC_RCUR (NREG * SLAB * 2)       // int[NREG*RSTRIDE]

#define MTILE 64
#define NTILES ((N_NODES + MTILE - 1) / MTILE)  // 782

#define AGGR_THREADS 512
#define AGGR_WAVES (AGGR_THREADS / 64)

__device__ __forceinline__ ushort_t f2bf(float f) {
    uint_t u = __float_as_uint(f);
    uint_t r = ((u >> 16) & 1u) + 0x7fffu;  // RNE
    return (ushort_t)((u + r) >> 16);
}

// native LDS float atomic add, NO memory clobber: data deps order it after
// the msg computation; asm-volatile program order keeps it before the
// explicit lgkmcnt drain (which has the clobber) + barrier.
__device__ __forceinline__ void lds_fadd(float* p, float v) {
    asm volatile("ds_add_f32 %0, %1" :: "v"((uint_t)(size_t)p), "v"(v));
}

// ---------------------------------------------------------------------------
// init: zero region cursors + stats replicas; block 0 detects int64 vs int32.
// ---------------------------------------------------------------------------
__global__ __launch_bounds__(256) void init_kernel(const int* __restrict__ ei,
                                                   int* __restrict__ flag,
                                                   int* __restrict__ rcur,
                                                   float* __restrict__ stats) {
    const int gtid = blockIdx.x * 256 + threadIdx.x;
    const int nth = gridDim.x * 256;
    for (int i = gtid; i < NREG * RSTRIDE; i += nth) rcur[i] = 0;
    if (gtid < NREP * 192) stats[gtid] = 0.f;
    if (blockIdx.x == 0) {
        __shared__ int s_any;
        if (threadIdx.x == 0) s_any = 0;
        __syncthreads();
        int nz = 0;
#pragma unroll
        for (int j = 0; j < 16; ++j) {
            const int p = 1 + 2 * (threadIdx.x * 16 + j) * 195;  // odd, <1.6M
            if (ei[p] != 0) nz = 1;
        }
        if (nz) atomicOr(&s_any, 1);
        __syncthreads();
        if (threadIdx.x == 0) *flag = s_any ? 0 : 1;
    }
}

// ---------------------------------------------------------------------------
// bin: single pass over edges. region r = dst>>6; pos = rcur[r]++ (atomic);
// slab[r*SLAB+pos] = {x=src, y=eid | dlocal<<20}. NT store. Replaces
// hist+scan+scatter (3 passes, 1.6M atomics) with 1 pass, 800K atomics.
// ---------------------------------------------------------------------------
__global__ __launch_bounds__(256) void bin_kernel(const int* __restrict__ ei,
                                                  const int* __restrict__ flag,
                                                  int* __restrict__ rcur,
                                                  int2* __restrict__ slab) {
    const int is64 = *flag;
    const int stride = gridDim.x * blockDim.x;
    for (int e = blockIdx.x * blockDim.x + threadIdx.x; e < N_EDGES; e += stride) {
        int s, d;
        if (is64) { s = ei[2 * e]; d = ei[2 * N_EDGES + 2 * e]; }
        else      { s = ei[e];     d = ei[N_EDGES + e]; }
        if ((uint_t)s < N_NODES && (uint_t)d < N_NODES) {
            const int r = d >> RBITS;
            const int dl = d & (RNODES - 1);
            const int pos = atomicAdd(&rcur[r * RSTRIDE], 1);
            if (pos < SLAB) {
                const uint_t packed = (uint_t)e | ((uint_t)dl << 20);
                const ull_t v = ((ull_t)packed << 32) | (uint_t)s;  // {x=s,y=packed}
                __builtin_nontemporal_store(v,
                    (ull_t*)&slab[(size_t)r * SLAB + pos]);
            }
        }
    }
}

// ---------------------------------------------------------------------------
// region_aggr v3: block = 64-node region, 512 threads (8 waves), LDS
// accumulator h[64][100]. Per 16-edge dense tile:
//   proj[16e x 96f] = ea[eids] @ We via 6x mfma 16x16x32 bf16
//   (A[m=t][k=q*8+j], C row m=q*4+r col t  [m89 layout])
// Epilogue restructured vs round 8 (the 530us bug): compute ALL 24 msg
// values into registers FIRST (x loads batch + overlap, no asm between),
// THEN burst the 24 ds_add_f32. Invalid lanes read x row 0 and add +0.0f
// (harmless: relu sums >= 0, no -0 hazard).
// ---------------------------------------------------------------------------
__global__ __launch_bounds__(AGGR_THREADS) void region_aggr_kernel(
    const float* __restrict__ x, const float* __restrict__ ea,
    const float* __restrict__ We, const float* __restrict__ be,
    const int2* __restrict__ slab, const int* __restrict__ rcur,
    float* __restrict__ hbuf) {
    __shared__ float h[RNODES][100];

    const int tid = threadIdx.x;
    const int r = blockIdx.x;
    for (int i = tid; i < RNODES * 100 / 4; i += AGGR_THREADS) {
        f32x4 z = {0.f, 0.f, 0.f, 0.f};
        ((f32x4*)&h[0][0])[i] = z;
    }

    const int lane = tid & 63;
    const int q = lane >> 4;
    const int t = lane & 15;
    const int w = tid >> 6;  // wave 0..7

    bf16x8 Bf[6];
    float ben[6];
#pragma unroll
    for (int f = 0; f < 6; ++f) {
        const int n = t + 16 * f;
#pragma unroll
        for (int j = 0; j < 8; ++j) {
            const int k = q * 8 + j;
            Bf[f][j] = (short)f2bf(We[k * 96 + n]);
        }
        ben[f] = be[n];
    }

    int cnt = rcur[r * RSTRIDE];
    if (cnt > SLAB) cnt = SLAB;
    const int2* lst = slab + (size_t)r * SLAB;
    const int ntile = (cnt + 15) >> 4;

    __syncthreads();  // h zeroed

    for (int tile = w; tile < ntile; tile += AGGR_WAVES) {
        const int base = tile * 16;
        const int rem = cnt - base;  // >= 1
        int eid = -1, src = 0, dl = 0;
        if (t < rem) {
            const int2 p = lst[base + t];
            src = p.x;
            eid = (int)((uint_t)p.y & 0xFFFFFu);
            dl = (int)((uint_t)p.y >> 20);
        }
        bf16x8 A = {0, 0, 0, 0, 0, 0, 0, 0};
        if (eid >= 0) {
            const float* row = ea + (size_t)eid * 32 + q * 8;
            f32x4 a0 = *(const f32x4*)(row);
            f32x4 a1 = *(const f32x4*)(row + 4);
#pragma unroll
            for (int j = 0; j < 4; ++j) {
                A[j] = (short)f2bf(a0[j]);
                A[4 + j] = (short)f2bf(a1[j]);
            }
        }

        f32x4 acc[6];
#pragma unroll
        for (int f = 0; f < 6; ++f) {
            f32x4 z = {0.f, 0.f, 0.f, 0.f};
            acc[f] = __builtin_amdgcn_mfma_f32_16x16x32_bf16(A, Bf[f], z, 0, 0, 0);
        }

        // ---- phase 1: compute all msg values (loads batch, no asm between)
        float msg[4][6];
        int dls[4];
#pragma unroll
        for (int rr = 0; rr < 4; ++rr) {
            const int m = q * 4 + rr;
            const int s_m = __shfl(src, m);
            const int dl_m = __shfl(dl, m);
            const bool valid = (m < rem);
            dls[rr] = valid ? dl_m : 0;
            const float* xrow = x + (size_t)(valid ? s_m : 0) * 96;
#pragma unroll
            for (int f = 0; f < 6; ++f) {
                float v = acc[f][rr] + ben[f] + xrow[t + 16 * f];
                v = v > 0.f ? v : 0.f;
                msg[rr][f] = valid ? v : 0.f;
            }
        }
        // ---- phase 2: burst the LDS atomics
#pragma unroll
        for (int rr = 0; rr < 4; ++rr)
#pragma unroll
            for (int f = 0; f < 6; ++f)
                lds_fadd(&h[dls[rr]][t + 16 * f], msg[rr][f]);
    }

    // inline-asm ds ops are untracked: drain before the read phase.
    asm volatile("s_waitcnt lgkmcnt(0)" ::: "memory");
    __syncthreads();  // all tiles accumulated

    const int n0 = r * RNODES;
    for (int i = tid; i < RNODES * 96 / 4; i += AGGR_THREADS) {
        const int idx = i * 4;
        const int dl = idx / 96;
        const int c = idx - dl * 96;
        const int n = n0 + dl;
        if (n < N_NODES) {
            f32x4 hv = *(const f32x4*)&h[dl][c];
            const f32x4 xv = *(const f32x4*)(x + (size_t)n * 96 + c);
            hv[0] += xv[0]; hv[1] += xv[1]; hv[2] += xv[2]; hv[3] += xv[3];
            *(f32x4*)(hbuf + (size_t)n * 96 + c) = hv;
        }
    }
}

// ---------------------------------------------------------------------------
// mlp: 64-node tile, 256 threads, fp32 register-tiled.
// stats atomics striped over NREP replicas to break line contention.
// ---------------------------------------------------------------------------
__global__ __launch_bounds__(256) void mlp_kernel(
    float* buf, const float* __restrict__ W1g, const float* __restrict__ b1g,
    const float* __restrict__ W2g, const float* __restrict__ b2g,
    float* __restrict__ stats) {
    __shared__ float Ws[96 * 96];
    __shared__ float hsT[96][68];

    const int tid = threadIdx.x;
    const int fg = tid & 15;
    const int ng = tid >> 4;
    const int n0 = blockIdx.x * MTILE;

    for (int i = tid; i < 96 * 96 / 4; i += 256)
        ((f32x4*)Ws)[i] = ((const f32x4*)W1g)[i];
    for (int i = tid; i < MTILE * 96 / 4; i += 256) {
        const int base = i * 4;
        const int nn = base / 96, k = base - nn * 96;
        f32x4 v = {0.f, 0.f, 0.f, 0.f};
        if (n0 + nn < N_NODES)
            v = *(const f32x4*)(buf + (size_t)(n0 + nn) * 96 + k);
        hsT[k][nn] = v[0]; hsT[k + 1][nn] = v[1];
        hsT[k + 2][nn] = v[2]; hsT[k + 3][nn] = v[3];
    }
    __syncthreads();

    float acc[4][6];
#pragma unroll
    for (int ff = 0; ff < 6; ++ff) {
        const float b = b1g[6 * fg + ff];
        acc[0][ff] = b; acc[1][ff] = b; acc[2][ff] = b; acc[3][ff] = b;
    }
    for (int k = 0; k < 96; ++k) {
        const f32x4 a = *(const f32x4*)&hsT[k][4 * ng];
        const float* wr = &Ws[k * 96 + 6 * fg];
        const f32x2 w01 = *(const f32x2*)(wr);
        const f32x2 w23 = *(const f32x2*)(wr + 2);
        const f32x2 w45 = *(const f32x2*)(wr + 4);
        const float w[6] = {w01[0], w01[1], w23[0], w23[1], w45[0], w45[1]};
#pragma unroll
        for (int nn = 0; nn < 4; ++nn)
#pragma unroll
            for (int ff = 0; ff < 6; ++ff) acc[nn][ff] += a[nn] * w[ff];
    }
    __syncthreads();

#pragma unroll
    for (int nn = 0; nn < 4; ++nn)
#pragma unroll
        for (int ff = 0; ff < 6; ++ff) {
            float v = acc[nn][ff];
            hsT[6 * fg + ff][4 * ng + nn] = v > 0.f ? v : 0.f;
        }
    for (int i = tid; i < 96 * 96 / 4; i += 256)
        ((f32x4*)Ws)[i] = ((const f32x4*)W2g)[i];
    __syncthreads();

#pragma unroll
    for (int ff = 0; ff < 6; ++ff) {
        const float b = b2g[6 * fg + ff];
        acc[0][ff] = b; acc[1][ff] = b; acc[2][ff] = b; acc[3][ff] = b;
    }
    for (int k = 0; k < 96; ++k) {
        const f32x4 a = *(const f32x4*)&hsT[k][4 * ng];
        const float* wr = &Ws[k * 96 + 6 * fg];
        const f32x2 w01 = *(const f32x2*)(wr);
        const f32x2 w23 = *(const f32x2*)(wr + 2);
        const f32x2 w45 = *(const f32x2*)(wr + 4);
        const float w[6] = {w01[0], w01[1], w23[0], w23[1], w45[0], w45[1]};
#pragma unroll
        for (int nn = 0; nn < 4; ++nn)
#pragma unroll
            for (int ff = 0; ff < 6; ++ff) acc[nn][ff] += a[nn] * w[ff];
    }

#pragma unroll
    for (int nn = 0; nn < 4; ++nn) {
        const int n = n0 + 4 * ng + nn;
        if (n < N_NODES) {
            float* o = buf + (size_t)n * 96 + 6 * fg;
            *(f32x2*)(o)     = (f32x2){acc[nn][0], acc[nn][1]};
            *(f32x2*)(o + 2) = (f32x2){acc[nn][2], acc[nn][3]};
            *(f32x2*)(o + 4) = (f32x2){acc[nn][4], acc[nn][5]};
        }
    }

    __syncthreads();
#pragma unroll
    for (int nn = 0; nn < 4; ++nn)
#pragma unroll
        for (int ff = 0; ff < 6; ++ff)
            hsT[6 * fg + ff][4 * ng + nn] = acc[nn][ff];
    __syncthreads();

    if (tid < 96) {
        int nmax = N_NODES - n0;
        if (nmax > MTILE) nmax = MTILE;
        float s = 0.f, s2 = 0.f;
        for (int n = 0; n < nmax; ++n) {
            const float v = hsT[tid][n];
            s += v; s2 += v * v;
        }
        float* st = stats + (blockIdx.x & (NREP - 1)) * 192;
        atomicAdd(&st[tid], s);
        atomicAdd(&st[96 + tid], s2);
    }
}

// ---------------------------------------------------------------------------
// bn: sum stat replicas, finalize + affine + ReLU, float4 streaming.
// ---------------------------------------------------------------------------
__global__ __launch_bounds__(256) void bn_kernel(
    const float* __restrict__ h2, const float* __restrict__ stats,
    const float* __restrict__ gamma, const float* __restrict__ beta,
    float* __restrict__ out) {
    __shared__ float sc[96], sh[96];
    const int tid = threadIdx.x;
    if (tid < 96) {
        float s1 = 0.f, s2 = 0.f;
#pragma unroll
        for (int r = 0; r < NREP; ++r) {
            s1 += stats[r * 192 + tid];
            s2 += stats[r * 192 + 96 + tid];
        }
        const float inv_n = 1.f / (float)N_NODES;
        const float mean = s1 * inv_n;
        float var = s2 * inv_n - mean * mean;
        var = var > 0.f ? var : 0.f;
        const float s = gamma[tid] * rsqrtf(var + BN_EPS);
        sc[tid] = s;
        sh[tid] = beta[tid] - mean * s;
    }
    __syncthreads();
    const int total4 = N_NODES * 96 / 4;
    for (int i = blockIdx.x * blockDim.x + tid; i < total4;
         i += gridDim.x * blockDim.x) {
        f32x4 v = ((const f32x4*)h2)[i];
        const int jb = (i * 4) % 96;
#pragma unroll
        for (int c = 0; c < 4; ++c) {
            float u = v[c] * sc[jb + c] + sh[jb + c];
            v[c] = u > 0.f ? u : 0.f;
        }
        ((f32x4*)out)[i] = v;
    }
}

// ---------------------------------------------------------------------------
extern "C" void kernel_launch(void* const* d_in, const int* in_sizes, int n_in,
                              void* d_out, int out_size, void* d_ws,
                              size_t ws_size, hipStream_t stream) {
    const float* x     = (const float*)d_in[0];
    const int*   ei    = (const int*)d_in[1];
    const float* ea    = (const float*)d_in[2];
    const float* We    = (const float*)d_in[3];
    const float* be    = (const float*)d_in[4];
    const float* W1    = (const float*)d_in[5];
    const float* b1    = (const float*)d_in[6];
    const float* W2    = (const float*)d_in[7];
    const float* b2    = (const float*)d_in[8];
    const float* gamma = (const float*)d_in[9];
    const float* beta  = (const float*)d_in[10];
    float* out = (float*)d_out;

    float* ws    = (float*)d_ws;
    float* hbuf  = ws;
    float* stats = ws + OFF_STATS;
    int*   flagp = (int*)(ws + OFF_FLAG);

    int*  scratch = (int*)d_out;
    int2* slab    = (int2*)(scratch + SC_SLAB);
    int*  rcur    = scratch + SC_RCUR;

    init_kernel<<<64, 256, 0, stream>>>(ei, flagp, rcur, stats);
    bin_kernel<<<1024, 256, 0, stream>>>(ei, flagp, rcur, slab);
    region_aggr_kernel<<<NREG, AGGR_THREADS, 0, stream>>>(x, ea, We, be, slab,
                                                          rcur, hbuf);
    mlp_kernel<<<NTILES, 256, 0, stream>>>(hbuf, W1, b1, W2, b2, stats);
    bn_kernel<<<1024, 256, 0, stream>>>(hbuf, stats, gamma, beta, out);
}